// Round 1
// baseline (341.420 us; speedup 1.0000x reference)
//
#include <hip/hip_runtime.h>
#include <hip/hip_bf16.h>
#include <stdint.h>

#define SEQLEN 4096
#define DMODEL 1024

typedef uint16_t u16;
typedef uint32_t u32;

typedef __bf16 bf16x8 __attribute__((ext_vector_type(8)));
typedef float  f32x4  __attribute__((ext_vector_type(4)));
typedef u16    u16x8  __attribute__((ext_vector_type(8)));
typedef u16    u16x4  __attribute__((ext_vector_type(4)));

// ---------------- helpers ----------------
__device__ __forceinline__ u16 f2bf(float f) {
  union { float f; u32 u; } a; a.f = f;
  return (u16)((a.u + 0x7FFFu + ((a.u >> 16) & 1u)) >> 16);  // RNE
}
__device__ __forceinline__ float bf2f(u16 h) {
  union { u32 u; float f; } a; a.u = ((u32)h) << 16;
  return a.f;
}

__device__ __forceinline__ void gl_lds16(const u16* g, u16* l) {
  __builtin_amdgcn_global_load_lds(
      (const __attribute__((address_space(1))) void*)g,
      (__attribute__((address_space(3))) void*)l,
      16, 0, 0);
}

// Stage a [128 rows][64 halves] tile from global row-major (ld halves) into
// LDS. LDS dest is linear (global_load_lds requirement); the XOR chunk
// swizzle is applied on the per-lane GLOBAL source address (rule #21), and
// un-applied at fragment-read time.
__device__ __forceinline__ void stage_tile(const u16* __restrict__ g, int ld,
                                           int row0, int k0, u16* lds, int tid) {
#pragma unroll
  for (int it = 0; it < 4; ++it) {
    int u = tid + 256 * it;        // 16B-chunk index 0..1023
    int row = u >> 3;
    int cg = (u & 7) ^ (row & 7);  // swizzled source chunk
    gl_lds16(g + (size_t)(row0 + row) * ld + (size_t)(k0 + cg * 8), lds + u * 8);
  }
}

// Fragment read: 8 contiguous k-halves for MFMA 16x16x32 (A: row=m, B: row=n)
__device__ __forceinline__ bf16x8 ld_frag(const u16* lds, int row, int chunk) {
  return *(const bf16x8*)(lds + row * 64 + ((chunk ^ (row & 7)) << 3));
}

#define MFMA16(c, a, b) c = __builtin_amdgcn_mfma_f32_16x16x32_bf16(a, b, c, 0, 0, 0)

// ---------------- prep kernels ----------------
__global__ void split_x_kernel(const float* __restrict__ x,
                               u16* __restrict__ xh, u16* __restrict__ xl) {
  const int total = SEQLEN * DMODEL / 4;
  for (int idx = blockIdx.x * 256 + threadIdx.x; idx < total; idx += gridDim.x * 256) {
    float4 f = ((const float4*)x)[idx];
    float ff[4] = {f.x, f.y, f.z, f.w};
    union { u16x4 v; u16 s[4]; } h, l;
#pragma unroll
    for (int uu = 0; uu < 4; ++uu) {
      u16 hi = f2bf(ff[uu]);
      h.s[uu] = hi;
      l.s[uu] = f2bf(ff[uu] - bf2f(hi));
    }
    ((u16x4*)xh)[idx] = h.v;
    ((u16x4*)xl)[idx] = l.v;
  }
}

// W [1024 k][1024 n] fp32 -> WT hi/lo bf16 [1024 n][1024 k]
__global__ void transpose_w_kernel(const float* __restrict__ W,
                                   u16* __restrict__ wth, u16* __restrict__ wtl) {
  __shared__ float tile[64][65];
  int n0 = (blockIdx.x & 15) * 64;
  int k0 = (blockIdx.x >> 4) * 64;
  int c = threadIdx.x & 63, r0 = threadIdx.x >> 6;
#pragma unroll
  for (int rr = 0; rr < 16; ++rr) {
    int r = r0 * 16 + rr;
    tile[r][c] = W[(size_t)(k0 + r) * DMODEL + n0 + c];
  }
  __syncthreads();
#pragma unroll
  for (int rr = 0; rr < 16; ++rr) {
    int n = r0 * 16 + rr;
    float f = tile[c][n];
    u16 hi = f2bf(f);
    wth[(size_t)(n0 + n) * DMODEL + k0 + c] = hi;
    wtl[(size_t)(n0 + n) * DMODEL + k0 + c] = f2bf(f - bf2f(hi));
  }
}

// ---------------- projection GEMM ----------------
// C = A@B^T(+bias), A=[4096][1024] hi/lo, B^T given as [n][k] hi/lo.
// THREE: 3-term split accumulation. SPLITOUT: write (hi,lo) [row][col],
// else write transposed single bf16 outT[col][row] (for V).
template <bool THREE, bool SPLITOUT>
__global__ __launch_bounds__(256, 2) void proj_kernel(
    const u16* __restrict__ Ah, const u16* __restrict__ Al,
    const u16* __restrict__ Bh, const u16* __restrict__ Bl,
    const float* __restrict__ bias, float scale,
    u16* __restrict__ outh, u16* __restrict__ outl, u16* __restrict__ outT) {
  __shared__ __align__(16) u16 sAh[128 * 64];
  __shared__ __align__(16) u16 sBh[128 * 64];
  __shared__ __align__(16) u16 sAl[THREE ? 128 * 64 : 8];
  __shared__ __align__(16) u16 sBl[THREE ? 128 * 64 : 8];

  int tid = threadIdx.x;
  int lane = tid & 63, wid = tid >> 6;
  int wr = (wid >> 1) * 64, wc = (wid & 1) * 64;
  int r = lane & 15, g = lane >> 4;
  int m0 = blockIdx.x * 128, n0 = blockIdx.y * 128;

  f32x4 acc[4][4];
#pragma unroll
  for (int i = 0; i < 4; ++i)
#pragma unroll
    for (int j = 0; j < 4; ++j) acc[i][j] = (f32x4){0.f, 0.f, 0.f, 0.f};

  for (int step = 0; step < DMODEL / 64; ++step) {
    int k0 = step * 64;
    __syncthreads();
    stage_tile(Ah, DMODEL, m0, k0, sAh, tid);
    stage_tile(Bh, DMODEL, n0, k0, sBh, tid);
    if (THREE) {
      stage_tile(Al, DMODEL, m0, k0, sAl, tid);
      stage_tile(Bl, DMODEL, n0, k0, sBl, tid);
    }
    __syncthreads();
#pragma unroll
    for (int ks = 0; ks < 2; ++ks) {
      bf16x8 fa[4], fb[4], fal[4], fbl[4];
#pragma unroll
      for (int i = 0; i < 4; ++i) {
        fa[i] = ld_frag(sAh, wr + i * 16 + r, ks * 4 + g);
        fb[i] = ld_frag(sBh, wc + i * 16 + r, ks * 4 + g);
      }
      if (THREE) {
#pragma unroll
        for (int i = 0; i < 4; ++i) {
          fal[i] = ld_frag(sAl, wr + i * 16 + r, ks * 4 + g);
          fbl[i] = ld_frag(sBl, wc + i * 16 + r, ks * 4 + g);
        }
      }
#pragma unroll
      for (int i = 0; i < 4; ++i)
#pragma unroll
        for (int j = 0; j < 4; ++j) {
          MFMA16(acc[i][j], fa[i], fb[j]);
          if (THREE) {
            MFMA16(acc[i][j], fa[i], fbl[j]);
            MFMA16(acc[i][j], fal[i], fb[j]);
          }
        }
    }
  }
#pragma unroll
  for (int i = 0; i < 4; ++i)
#pragma unroll
    for (int j = 0; j < 4; ++j) {
      int col = n0 + wc + j * 16 + r;
      float bv = bias[col];
#pragma unroll
      for (int t = 0; t < 4; ++t) {
        int row = m0 + wr + i * 16 + g * 4 + t;
        float v = (acc[i][j][t] + bv) * scale;
        if (SPLITOUT) {
          u16 hi = f2bf(v);
          outh[(size_t)row * DMODEL + col] = hi;
          outl[(size_t)row * DMODEL + col] = f2bf(v - bf2f(hi));
        } else {
          outT[(size_t)col * SEQLEN + row] = f2bf(v);  // transposed V
        }
      }
    }
}

// ---------------- scores + per-tile softmax ----------------
// S_tile = (q/32)@k^T for a 128x128 tile (fp32, split-bf16 3-term), then
// P' = exp(S - rowmax_tile) in bf16, plus per-(row,tile) max & sum stats.
__global__ __launch_bounds__(256, 2) void scores_kernel(
    const u16* __restrict__ qh, const u16* __restrict__ ql,
    const u16* __restrict__ kh, const u16* __restrict__ kl,
    u16* __restrict__ P, float* __restrict__ mloc, float* __restrict__ tsum) {
  __shared__ __align__(16) float sS[128 * 129];  // 66048B; also staging alias
  u16* sAh = (u16*)sS;
  u16* sAl = sAh + 128 * 64;
  u16* sBh = sAl + 128 * 64;
  u16* sBl = sBh + 128 * 64;

  int tid = threadIdx.x;
  int lane = tid & 63, wid = tid >> 6;
  int wr = (wid >> 1) * 64, wc = (wid & 1) * 64;
  int r = lane & 15, g = lane >> 4;
  int m0 = blockIdx.x * 128, n0 = blockIdx.y * 128;

  f32x4 acc[4][4];
#pragma unroll
  for (int i = 0; i < 4; ++i)
#pragma unroll
    for (int j = 0; j < 4; ++j) acc[i][j] = (f32x4){0.f, 0.f, 0.f, 0.f};

  for (int step = 0; step < DMODEL / 64; ++step) {
    int k0 = step * 64;
    __syncthreads();
    stage_tile(qh, DMODEL, m0, k0, sAh, tid);
    stage_tile(kh, DMODEL, n0, k0, sBh, tid);
    stage_tile(ql, DMODEL, m0, k0, sAl, tid);
    stage_tile(kl, DMODEL, n0, k0, sBl, tid);
    __syncthreads();
#pragma unroll
    for (int ks = 0; ks < 2; ++ks) {
      bf16x8 fa[4], fb[4], fal[4], fbl[4];
#pragma unroll
      for (int i = 0; i < 4; ++i) {
        fa[i] = ld_frag(sAh, wr + i * 16 + r, ks * 4 + g);
        fb[i] = ld_frag(sBh, wc + i * 16 + r, ks * 4 + g);
        fal[i] = ld_frag(sAl, wr + i * 16 + r, ks * 4 + g);
        fbl[i] = ld_frag(sBl, wc + i * 16 + r, ks * 4 + g);
      }
#pragma unroll
      for (int i = 0; i < 4; ++i)
#pragma unroll
        for (int j = 0; j < 4; ++j) {
          MFMA16(acc[i][j], fa[i], fb[j]);
          MFMA16(acc[i][j], fa[i], fbl[j]);
          MFMA16(acc[i][j], fal[i], fb[j]);
        }
    }
  }
  __syncthreads();  // staging reads done; reuse LDS as fp32 S tile
#pragma unroll
  for (int i = 0; i < 4; ++i)
#pragma unroll
    for (int j = 0; j < 4; ++j)
#pragma unroll
      for (int t = 0; t < 4; ++t)
        sS[(wr + i * 16 + g * 4 + t) * 129 + wc + j * 16 + r] = acc[i][j][t];
  __syncthreads();

  int rt = tid >> 1, h = tid & 1;  // 2 threads per row, 64 cols each
  const float* rowp = sS + rt * 129 + h * 64;
  float mx = -3.0e38f;
#pragma unroll 16
  for (int c = 0; c < 64; ++c) mx = fmaxf(mx, rowp[c]);
  mx = fmaxf(mx, __shfl_xor(mx, 1));

  float ssum = 0.f;
  int grow = m0 + rt;
  u16* pout = P + (size_t)grow * SEQLEN + n0 + h * 64;
#pragma unroll
  for (int c8 = 0; c8 < 8; ++c8) {
    union { u16 s[8]; u16x8 v; } tmp;
#pragma unroll
    for (int uu = 0; uu < 8; ++uu) {
      float e = exp2f((rowp[c8 * 8 + uu] - mx) * 1.4426950408889634f);
      ssum += e;
      tmp.s[uu] = f2bf(e);
    }
    *(u16x8*)(pout + c8 * 8) = tmp.v;
  }
  ssum += __shfl_xor(ssum, 1);
  if (h == 0) {
    mloc[(size_t)blockIdx.y * SEQLEN + grow] = mx;
    tsum[(size_t)blockIdx.y * SEQLEN + grow] = ssum;
  }
}

// ---------------- softmax finalize ----------------
__global__ void finalize_kernel(const float* __restrict__ mloc,
                                const float* __restrict__ tsum,
                                float* __restrict__ rowscale) {
  int rr = blockIdx.x * 256 + threadIdx.x;
  if (rr >= SEQLEN) return;
  float M = -3.0e38f;
#pragma unroll
  for (int t = 0; t < 32; ++t) M = fmaxf(M, mloc[t * SEQLEN + rr]);
  float l = 0.f;
#pragma unroll
  for (int t = 0; t < 32; ++t)
    l += tsum[t * SEQLEN + rr] * exp2f((mloc[t * SEQLEN + rr] - M) * 1.4426950408889634f);
  float inv = 1.0f / l;
#pragma unroll
  for (int t = 0; t < 32; ++t)
    rowscale[t * SEQLEN + rr] = exp2f((mloc[t * SEQLEN + rr] - M) * 1.4426950408889634f) * inv;
}

__global__ void pnorm_kernel(u16* __restrict__ P, const float* __restrict__ rowscale) {
  const int total = SEQLEN * SEQLEN / 8;
  for (int idx = blockIdx.x * 256 + threadIdx.x; idx < total; idx += gridDim.x * 256) {
    int rrow = idx >> 9;
    int c8 = idx & 511;
    int t = c8 >> 4;
    float sc = rowscale[t * SEQLEN + rrow];
    union { u16x8 v; u16 s[8]; } d;
    d.v = ((u16x8*)P)[idx];
#pragma unroll
    for (int uu = 0; uu < 8; ++uu) d.s[uu] = f2bf(bf2f(d.s[uu]) * sc);
    ((u16x8*)P)[idx] = d.v;
  }
}

// ---------------- PV GEMM ----------------
__global__ __launch_bounds__(256, 2) void pv_kernel(const u16* __restrict__ P,
                                                    const u16* __restrict__ vT,
                                                    float* __restrict__ out) {
  __shared__ __align__(16) u16 sA[128 * 64];
  __shared__ __align__(16) u16 sB[128 * 64];
  int tid = threadIdx.x;
  int lane = tid & 63, wid = tid >> 6;
  int wr = (wid >> 1) * 64, wc = (wid & 1) * 64;
  int r = lane & 15, g = lane >> 4;
  int m0 = blockIdx.x * 128, n0 = blockIdx.y * 128;

  f32x4 acc[4][4];
#pragma unroll
  for (int i = 0; i < 4; ++i)
#pragma unroll
    for (int j = 0; j < 4; ++j) acc[i][j] = (f32x4){0.f, 0.f, 0.f, 0.f};

  for (int step = 0; step < SEQLEN / 64; ++step) {
    int k0 = step * 64;
    __syncthreads();
    stage_tile(P, SEQLEN, m0, k0, sA, tid);
    stage_tile(vT, SEQLEN, n0, k0, sB, tid);
    __syncthreads();
#pragma unroll
    for (int ks = 0; ks < 2; ++ks) {
      bf16x8 fa[4], fb[4];
#pragma unroll
      for (int i = 0; i < 4; ++i) {
        fa[i] = ld_frag(sA, wr + i * 16 + r, ks * 4 + g);
        fb[i] = ld_frag(sB, wc + i * 16 + r, ks * 4 + g);
      }
#pragma unroll
      for (int i = 0; i < 4; ++i)
#pragma unroll
        for (int j = 0; j < 4; ++j) MFMA16(acc[i][j], fa[i], fb[j]);
    }
  }
#pragma unroll
  for (int i = 0; i < 4; ++i)
#pragma unroll
    for (int j = 0; j < 4; ++j)
#pragma unroll
      for (int t = 0; t < 4; ++t)
        out[(size_t)(m0 + wr + i * 16 + g * 4 + t) * DMODEL + n0 + wc + j * 16 + r] =
            acc[i][j][t];
}

// ---------------- launch ----------------
extern "C" void kernel_launch(void* const* d_in, const int* in_sizes, int n_in,
                              void* d_out, int out_size, void* d_ws, size_t ws_size,
                              hipStream_t stream) {
  (void)in_sizes; (void)n_in; (void)out_size; (void)ws_size;
  const float* x  = (const float*)d_in[0];
  const float* WQ = (const float*)d_in[1];
  const float* WK = (const float*)d_in[2];
  const float* WV = (const float*)d_in[3];
  const float* bQ = (const float*)d_in[4];
  const float* bK = (const float*)d_in[5];
  const float* bV = (const float*)d_in[6];
  float* out = (float*)d_out;
  char* ws = (char*)d_ws;
  const size_t MB = 1ull << 20;

  // Prep region [0,28MB) is dead after projections; P (32MB) overlays it.
  u16* xh   = (u16*)(ws + 0);
  u16* xl   = (u16*)(ws + 8 * MB);
  u16* wqh  = (u16*)(ws + 16 * MB);
  u16* wql  = (u16*)(ws + 18 * MB);
  u16* wkh  = (u16*)(ws + 20 * MB);
  u16* wkl  = (u16*)(ws + 22 * MB);
  u16* wvh  = (u16*)(ws + 24 * MB);
  u16* wvl  = (u16*)(ws + 26 * MB);
  u16* P    = (u16*)(ws + 0);  // 32MB, written after prep region is dead
  u16* qh   = (u16*)(ws + 32 * MB);
  u16* ql   = (u16*)(ws + 40 * MB);
  u16* kh   = (u16*)(ws + 48 * MB);
  u16* kl   = (u16*)(ws + 56 * MB);
  u16* vT   = (u16*)(ws + 64 * MB);
  float* mloc     = (float*)(ws + 72 * MB);
  float* tsum     = (float*)(ws + 72 * MB + 512 * 1024);
  float* rowscale = (float*)(ws + 73 * MB);

  split_x_kernel<<<2048, 256, 0, stream>>>(x, xh, xl);
  transpose_w_kernel<<<256, 256, 0, stream>>>(WQ, wqh, wql);
  transpose_w_kernel<<<256, 256, 0, stream>>>(WK, wkh, wkl);
  transpose_w_kernel<<<256, 256, 0, stream>>>(WV, wvh, wvl);

  dim3 gproj(32, 8);
  // Q: scaled by 1/sqrt(D)=1/32 before split; K: unscaled; both split hi/lo.
  proj_kernel<true, true><<<gproj, 256, 0, stream>>>(xh, xl, wqh, wql, bQ,
                                                     1.0f / 32.0f, qh, ql, nullptr);
  proj_kernel<true, true><<<gproj, 256, 0, stream>>>(xh, xl, wkh, wkl, bK,
                                                     1.0f, kh, kl, nullptr);
  // V: single-term bf16 is accurate enough; written transposed for PV.
  proj_kernel<false, false><<<gproj, 256, 0, stream>>>(xh, nullptr, wvh, nullptr, bV,
                                                       1.0f, nullptr, nullptr, vT);

  dim3 gsc(32, 32);
  scores_kernel<<<gsc, 256, 0, stream>>>(qh, ql, kh, kl, P, mloc, tsum);
  finalize_kernel<<<16, 256, 0, stream>>>(mloc, tsum, rowscale);
  pnorm_kernel<<<4096, 256, 0, stream>>>(P, rowscale);

  dim3 gpv(32, 8);
  pv_kernel<<<gpv, 256, 0, stream>>>(P, vT, out);
}

// Round 2
// 337.788 us; speedup vs baseline: 1.0108x; 1.0108x over previous
//
#include <hip/hip_runtime.h>
#include <hip/hip_bf16.h>
#include <stdint.h>

#define SEQLEN 4096
#define DMODEL 1024

typedef uint16_t u16;
typedef uint32_t u32;

typedef __bf16 bf16x8 __attribute__((ext_vector_type(8)));
typedef float  f32x4  __attribute__((ext_vector_type(4)));
typedef u16    u16x8  __attribute__((ext_vector_type(8)));
typedef u16    u16x4  __attribute__((ext_vector_type(4)));

// ---------------- helpers ----------------
__device__ __forceinline__ u16 f2bf(float f) {
  union { float f; u32 u; } a; a.f = f;
  return (u16)((a.u + 0x7FFFu + ((a.u >> 16) & 1u)) >> 16);  // RNE
}
__device__ __forceinline__ float bf2f(u16 h) {
  union { u32 u; float f; } a; a.u = ((u32)h) << 16;
  return a.f;
}

__device__ __forceinline__ void gl_lds16(const u16* g, u16* l) {
  __builtin_amdgcn_global_load_lds(
      (const __attribute__((address_space(1))) void*)g,
      (__attribute__((address_space(3))) void*)l,
      16, 0, 0);
}

// ---- staging: LDS dest linear (global_load_lds requirement); XOR swizzle
// applied on the per-lane GLOBAL source chunk (rule #21), undone at read.
// BK=64 tile: [128 rows][64 halves], swizzle c^(row&7) -> conflict-free.
__device__ __forceinline__ void stage64(const u16* __restrict__ g, int ld,
                                        int row0, int k0, u16* lds, int tid) {
#pragma unroll
  for (int it = 0; it < 4; ++it) {
    int u = tid + 256 * it;        // 16B-chunk index 0..1023
    int row = u >> 3;
    int cg = (u & 7) ^ (row & 7);
    gl_lds16(g + (size_t)(row0 + row) * ld + (size_t)(k0 + cg * 8), lds + u * 8);
  }
}
// BK=32 tile: [128 rows][32 halves], swizzle c^((row>>1)&3): 16 rows cover all
// eight 16B bank-slots twice -> 2-way aliasing (free).
__device__ __forceinline__ void stage32(const u16* __restrict__ g, int ld,
                                        int row0, int k0, u16* lds, int tid) {
#pragma unroll
  for (int it = 0; it < 2; ++it) {
    int u = tid + 256 * it;        // 16B-chunk index 0..511
    int row = u >> 2;
    int cg = (u & 3) ^ ((row >> 1) & 3);
    gl_lds16(g + (size_t)(row0 + row) * ld + (size_t)(k0 + cg * 8), lds + u * 8);
  }
}
__device__ __forceinline__ bf16x8 frag64(const u16* lds, int row, int chunk) {
  return *(const bf16x8*)(lds + row * 64 + ((chunk ^ (row & 7)) << 3));
}
__device__ __forceinline__ bf16x8 frag32(const u16* lds, int row, int chunk) {
  return *(const bf16x8*)(lds + row * 32 + ((chunk ^ ((row >> 1) & 3)) << 3));
}

#define MFMA16(c, a, b) c = __builtin_amdgcn_mfma_f32_16x16x32_bf16(a, b, c, 0, 0, 0)

// ---------------- prep kernels ----------------
__global__ void split_x_kernel(const float* __restrict__ x,
                               u16* __restrict__ xh, u16* __restrict__ xl) {
  const int total = SEQLEN * DMODEL / 4;
  for (int idx = blockIdx.x * 256 + threadIdx.x; idx < total; idx += gridDim.x * 256) {
    float4 f = ((const float4*)x)[idx];
    float ff[4] = {f.x, f.y, f.z, f.w};
    union { u16x4 v; u16 s[4]; } h, l;
#pragma unroll
    for (int uu = 0; uu < 4; ++uu) {
      u16 hi = f2bf(ff[uu]);
      h.s[uu] = hi;
      l.s[uu] = f2bf(ff[uu] - bf2f(hi));
    }
    ((u16x4*)xh)[idx] = h.v;
    ((u16x4*)xl)[idx] = l.v;
  }
}

// W [1024 k][1024 n] fp32 -> WT hi/lo bf16 [1024 n][1024 k]
__global__ void transpose_w_kernel(const float* __restrict__ W,
                                   u16* __restrict__ wth, u16* __restrict__ wtl) {
  __shared__ float tile[64][65];
  int n0 = (blockIdx.x & 15) * 64;
  int k0 = (blockIdx.x >> 4) * 64;
  int c = threadIdx.x & 63, r0 = threadIdx.x >> 6;
#pragma unroll
  for (int rr = 0; rr < 16; ++rr) {
    int r = r0 * 16 + rr;
    tile[r][c] = W[(size_t)(k0 + r) * DMODEL + n0 + c];
  }
  __syncthreads();
#pragma unroll
  for (int rr = 0; rr < 16; ++rr) {
    int n = r0 * 16 + rr;
    float f = tile[c][n];
    u16 hi = f2bf(f);
    wth[(size_t)(n0 + n) * DMODEL + k0 + c] = hi;
    wtl[(size_t)(n0 + n) * DMODEL + k0 + c] = f2bf(f - bf2f(hi));
  }
}

// ---------------- projection GEMM (double-buffered) ----------------
// C = A@B^T(+bias), A=[4096][1024] hi/lo, B^T given as [n][k] hi/lo.
// THREE: 3-term split accumulation (BK=32, 4 staged tiles).
// !THREE: single-term (BK=64, 2 staged tiles).
template <bool THREE, bool SPLITOUT>
__global__ __launch_bounds__(256, 2) void proj_kernel(
    const u16* __restrict__ Ah, const u16* __restrict__ Al,
    const u16* __restrict__ Bh, const u16* __restrict__ Bl,
    const float* __restrict__ bias, float scale,
    u16* __restrict__ outh, u16* __restrict__ outl, u16* __restrict__ outT) {
  __shared__ __align__(16) u16 st[32768];  // 64 KB: 2 buffers

  int tid = threadIdx.x;
  int lane = tid & 63, wid = tid >> 6;
  int wr = (wid >> 1) * 64, wc = (wid & 1) * 64;
  int r = lane & 15, g = lane >> 4;
  int m0 = blockIdx.x * 128, n0 = blockIdx.y * 128;

  f32x4 acc[4][4];
#pragma unroll
  for (int i = 0; i < 4; ++i)
#pragma unroll
    for (int j = 0; j < 4; ++j) acc[i][j] = (f32x4){0.f, 0.f, 0.f, 0.f};

  if (THREE) {
    // buffer stride 16384 u16; tiles of 4096 u16: [Ah, Al, Bh, Bl]
    stage32(Ah, DMODEL, m0, 0, st + 0 * 4096, tid);
    stage32(Al, DMODEL, m0, 0, st + 1 * 4096, tid);
    stage32(Bh, DMODEL, n0, 0, st + 2 * 4096, tid);
    stage32(Bl, DMODEL, n0, 0, st + 3 * 4096, tid);
    __syncthreads();
    int c = 0;
    for (int step = 0; step < DMODEL / 32; ++step) {
      if (step + 1 < DMODEL / 32) {
        int k0 = (step + 1) * 32;
        u16* nb = st + (c ^ 1) * 16384;
        stage32(Ah, DMODEL, m0, k0, nb + 0 * 4096, tid);
        stage32(Al, DMODEL, m0, k0, nb + 1 * 4096, tid);
        stage32(Bh, DMODEL, n0, k0, nb + 2 * 4096, tid);
        stage32(Bl, DMODEL, n0, k0, nb + 3 * 4096, tid);
      }
      const u16* cb = st + c * 16384;
      bf16x8 fa[4], fb[4], fal[4], fbl[4];
#pragma unroll
      for (int i = 0; i < 4; ++i) {
        fa[i]  = frag32(cb + 0 * 4096, wr + i * 16 + r, g);
        fal[i] = frag32(cb + 1 * 4096, wr + i * 16 + r, g);
        fb[i]  = frag32(cb + 2 * 4096, wc + i * 16 + r, g);
        fbl[i] = frag32(cb + 3 * 4096, wc + i * 16 + r, g);
      }
#pragma unroll
      for (int i = 0; i < 4; ++i)
#pragma unroll
        for (int j = 0; j < 4; ++j) {
          MFMA16(acc[i][j], fa[i], fb[j]);
          MFMA16(acc[i][j], fa[i], fbl[j]);
          MFMA16(acc[i][j], fal[i], fb[j]);
        }
      __syncthreads();
      c ^= 1;
    }
  } else {
    // buffer stride 16384 u16; tiles of 8192 u16: [Ah, Bh]
    stage64(Ah, DMODEL, m0, 0, st + 0 * 8192, tid);
    stage64(Bh, DMODEL, n0, 0, st + 1 * 8192, tid);
    __syncthreads();
    int c = 0;
    for (int step = 0; step < DMODEL / 64; ++step) {
      if (step + 1 < DMODEL / 64) {
        int k0 = (step + 1) * 64;
        u16* nb = st + (c ^ 1) * 16384;
        stage64(Ah, DMODEL, m0, k0, nb + 0 * 8192, tid);
        stage64(Bh, DMODEL, n0, k0, nb + 1 * 8192, tid);
      }
      const u16* cb = st + c * 16384;
#pragma unroll
      for (int ks = 0; ks < 2; ++ks) {
        bf16x8 fa[4], fb[4];
#pragma unroll
        for (int i = 0; i < 4; ++i) {
          fa[i] = frag64(cb + 0 * 8192, wr + i * 16 + r, ks * 4 + g);
          fb[i] = frag64(cb + 1 * 8192, wc + i * 16 + r, ks * 4 + g);
        }
#pragma unroll
        for (int i = 0; i < 4; ++i)
#pragma unroll
          for (int j = 0; j < 4; ++j) MFMA16(acc[i][j], fa[i], fb[j]);
      }
      __syncthreads();
      c ^= 1;
    }
  }

#pragma unroll
  for (int i = 0; i < 4; ++i)
#pragma unroll
    for (int j = 0; j < 4; ++j) {
      int col = n0 + wc + j * 16 + r;
      float bv = bias[col];
#pragma unroll
      for (int t = 0; t < 4; ++t) {
        int row = m0 + wr + i * 16 + g * 4 + t;
        float v = (acc[i][j][t] + bv) * scale;
        if (SPLITOUT) {
          u16 hi = f2bf(v);
          outh[(size_t)row * DMODEL + col] = hi;
          outl[(size_t)row * DMODEL + col] = f2bf(v - bf2f(hi));
        } else {
          outT[(size_t)col * SEQLEN + row] = f2bf(v);  // transposed V
        }
      }
    }
}

// ---------------- scores + per-tile softmax (double-buffered) ----------------
__global__ __launch_bounds__(256, 2) void scores_kernel(
    const u16* __restrict__ qh, const u16* __restrict__ ql,
    const u16* __restrict__ kh, const u16* __restrict__ kl,
    u16* __restrict__ P, float* __restrict__ mloc, float* __restrict__ tsum) {
  // 66048 B: staging (2 buf x 4 tiles x 8 KB = 64 KB) aliased with fp32 S tile
  __shared__ __align__(16) char smem[128 * 129 * 4];
  u16* st = (u16*)smem;
  float* sS = (float*)smem;

  int tid = threadIdx.x;
  int lane = tid & 63, wid = tid >> 6;
  int wr = (wid >> 1) * 64, wc = (wid & 1) * 64;
  int r = lane & 15, g = lane >> 4;
  int m0 = blockIdx.x * 128, n0 = blockIdx.y * 128;

  f32x4 acc[4][4];
#pragma unroll
  for (int i = 0; i < 4; ++i)
#pragma unroll
    for (int j = 0; j < 4; ++j) acc[i][j] = (f32x4){0.f, 0.f, 0.f, 0.f};

  stage32(qh, DMODEL, m0, 0, st + 0 * 4096, tid);
  stage32(ql, DMODEL, m0, 0, st + 1 * 4096, tid);
  stage32(kh, DMODEL, n0, 0, st + 2 * 4096, tid);
  stage32(kl, DMODEL, n0, 0, st + 3 * 4096, tid);
  __syncthreads();
  int c = 0;
  for (int step = 0; step < DMODEL / 32; ++step) {
    if (step + 1 < DMODEL / 32) {
      int k0 = (step + 1) * 32;
      u16* nb = st + (c ^ 1) * 16384;
      stage32(qh, DMODEL, m0, k0, nb + 0 * 4096, tid);
      stage32(ql, DMODEL, m0, k0, nb + 1 * 4096, tid);
      stage32(kh, DMODEL, n0, k0, nb + 2 * 4096, tid);
      stage32(kl, DMODEL, n0, k0, nb + 3 * 4096, tid);
    }
    const u16* cb = st + c * 16384;
    bf16x8 fa[4], fb[4], fal[4], fbl[4];
#pragma unroll
    for (int i = 0; i < 4; ++i) {
      fa[i]  = frag32(cb + 0 * 4096, wr + i * 16 + r, g);
      fal[i] = frag32(cb + 1 * 4096, wr + i * 16 + r, g);
      fb[i]  = frag32(cb + 2 * 4096, wc + i * 16 + r, g);
      fbl[i] = frag32(cb + 3 * 4096, wc + i * 16 + r, g);
    }
#pragma unroll
    for (int i = 0; i < 4; ++i)
#pragma unroll
      for (int j = 0; j < 4; ++j) {
        MFMA16(acc[i][j], fa[i], fb[j]);
        MFMA16(acc[i][j], fa[i], fbl[j]);
        MFMA16(acc[i][j], fal[i], fb[j]);
      }
    __syncthreads();
    c ^= 1;
  }

  // staging done (last loop iteration ended with a barrier); reuse LDS as S
#pragma unroll
  for (int i = 0; i < 4; ++i)
#pragma unroll
    for (int j = 0; j < 4; ++j)
#pragma unroll
      for (int t = 0; t < 4; ++t)
        sS[(wr + i * 16 + g * 4 + t) * 129 + wc + j * 16 + r] = acc[i][j][t];
  __syncthreads();

  int rt = tid >> 1, h = tid & 1;  // 2 threads per row, 64 cols each
  const float* rowp = sS + rt * 129 + h * 64;
  float mx = -3.0e38f;
#pragma unroll 16
  for (int cc = 0; cc < 64; ++cc) mx = fmaxf(mx, rowp[cc]);
  mx = fmaxf(mx, __shfl_xor(mx, 1));

  float ssum = 0.f;
  int grow = m0 + rt;
  u16* pout = P + (size_t)grow * SEQLEN + n0 + h * 64;
#pragma unroll
  for (int c8 = 0; c8 < 8; ++c8) {
    union { u16 s[8]; u16x8 v; } tmp;
#pragma unroll
    for (int uu = 0; uu < 8; ++uu) {
      float e = exp2f((rowp[c8 * 8 + uu] - mx) * 1.4426950408889634f);
      ssum += e;
      tmp.s[uu] = f2bf(e);
    }
    *(u16x8*)(pout + c8 * 8) = tmp.v;
  }
  ssum += __shfl_xor(ssum, 1);
  if (h == 0) {
    mloc[(size_t)blockIdx.y * SEQLEN + grow] = mx;
    tsum[(size_t)blockIdx.y * SEQLEN + grow] = ssum;
  }
}

// ---------------- softmax finalize ----------------
__global__ void finalize_kernel(const float* __restrict__ mloc,
                                const float* __restrict__ tsum,
                                float* __restrict__ rowscale) {
  int rr = blockIdx.x * 256 + threadIdx.x;
  if (rr >= SEQLEN) return;
  float M = -3.0e38f;
#pragma unroll
  for (int t = 0; t < 32; ++t) M = fmaxf(M, mloc[t * SEQLEN + rr]);
  float l = 0.f;
#pragma unroll
  for (int t = 0; t < 32; ++t)
    l += tsum[t * SEQLEN + rr] * exp2f((mloc[t * SEQLEN + rr] - M) * 1.4426950408889634f);
  float inv = 1.0f / l;
#pragma unroll
  for (int t = 0; t < 32; ++t)
    rowscale[t * SEQLEN + rr] = exp2f((mloc[t * SEQLEN + rr] - M) * 1.4426950408889634f) * inv;
}

__global__ void pnorm_kernel(u16* __restrict__ P, const float* __restrict__ rowscale) {
  const int total = SEQLEN * SEQLEN / 8;
  for (int idx = blockIdx.x * 256 + threadIdx.x; idx < total; idx += gridDim.x * 256) {
    int rrow = idx >> 9;
    int c8 = idx & 511;
    int t = c8 >> 4;
    float sc = rowscale[t * SEQLEN + rrow];
    union { u16x8 v; u16 s[8]; } d;
    d.v = ((u16x8*)P)[idx];
#pragma unroll
    for (int uu = 0; uu < 8; ++uu) d.s[uu] = f2bf(bf2f(d.s[uu]) * sc);
    ((u16x8*)P)[idx] = d.v;
  }
}

// ---------------- PV GEMM (double-buffered) ----------------
__global__ __launch_bounds__(256, 2) void pv_kernel(const u16* __restrict__ P,
                                                    const u16* __restrict__ vT,
                                                    float* __restrict__ out) {
  __shared__ __align__(16) u16 st[32768];  // 64 KB: 2 buffers x [A(16KB), B(16KB)]
  int tid = threadIdx.x;
  int lane = tid & 63, wid = tid >> 6;
  int wr = (wid >> 1) * 64, wc = (wid & 1) * 64;
  int r = lane & 15, g = lane >> 4;
  int m0 = blockIdx.x * 128, n0 = blockIdx.y * 128;

  f32x4 acc[4][4];
#pragma unroll
  for (int i = 0; i < 4; ++i)
#pragma unroll
    for (int j = 0; j < 4; ++j) acc[i][j] = (f32x4){0.f, 0.f, 0.f, 0.f};

  stage64(P, SEQLEN, m0, 0, st + 0 * 8192, tid);
  stage64(vT, SEQLEN, n0, 0, st + 1 * 8192, tid);
  __syncthreads();
  int c = 0;
  for (int step = 0; step < SEQLEN / 64; ++step) {
    if (step + 1 < SEQLEN / 64) {
      int k0 = (step + 1) * 64;
      u16* nb = st + (c ^ 1) * 16384;
      stage64(P, SEQLEN, m0, k0, nb + 0 * 8192, tid);
      stage64(vT, SEQLEN, n0, k0, nb + 1 * 8192, tid);
    }
    const u16* cb = st + c * 16384;
#pragma unroll
    for (int ks = 0; ks < 2; ++ks) {
      bf16x8 fa[4], fb[4];
#pragma unroll
      for (int i = 0; i < 4; ++i) {
        fa[i] = frag64(cb + 0 * 8192, wr + i * 16 + r, ks * 4 + g);
        fb[i] = frag64(cb + 1 * 8192, wc + i * 16 + r, ks * 4 + g);
      }
#pragma unroll
      for (int i = 0; i < 4; ++i)
#pragma unroll
        for (int j = 0; j < 4; ++j) MFMA16(acc[i][j], fa[i], fb[j]);
    }
    __syncthreads();
    c ^= 1;
  }
#pragma unroll
  for (int i = 0; i < 4; ++i)
#pragma unroll
    for (int j = 0; j < 4; ++j)
#pragma unroll
      for (int t = 0; t < 4; ++t)
        out[(size_t)(m0 + wr + i * 16 + g * 4 + t) * DMODEL + n0 + wc + j * 16 + r] =
            acc[i][j][t];
}

// ---------------- launch ----------------
extern "C" void kernel_launch(void* const* d_in, const int* in_sizes, int n_in,
                              void* d_out, int out_size, void* d_ws, size_t ws_size,
                              hipStream_t stream) {
  (void)in_sizes; (void)n_in; (void)out_size; (void)ws_size;
  const float* x  = (const float*)d_in[0];
  const float* WQ = (const float*)d_in[1];
  const float* WK = (const float*)d_in[2];
  const float* WV = (const float*)d_in[3];
  const float* bQ = (const float*)d_in[4];
  const float* bK = (const float*)d_in[5];
  const float* bV = (const float*)d_in[6];
  float* out = (float*)d_out;
  char* ws = (char*)d_ws;
  const size_t MB = 1ull << 20;

  // Prep region [0,28MB) is dead after projections; P (32MB) overlays it.
  u16* xh   = (u16*)(ws + 0);
  u16* xl   = (u16*)(ws + 8 * MB);
  u16* wqh  = (u16*)(ws + 16 * MB);
  u16* wql  = (u16*)(ws + 18 * MB);
  u16* wkh  = (u16*)(ws + 20 * MB);
  u16* wkl  = (u16*)(ws + 22 * MB);
  u16* wvh  = (u16*)(ws + 24 * MB);
  u16* wvl  = (u16*)(ws + 26 * MB);
  u16* P    = (u16*)(ws + 0);  // 32MB, written after prep region is dead
  u16* qh   = (u16*)(ws + 32 * MB);
  u16* ql   = (u16*)(ws + 40 * MB);
  u16* kh   = (u16*)(ws + 48 * MB);
  u16* kl   = (u16*)(ws + 56 * MB);
  u16* vT   = (u16*)(ws + 64 * MB);
  float* mloc     = (float*)(ws + 72 * MB);
  float* tsum     = (float*)(ws + 72 * MB + 512 * 1024);
  float* rowscale = (float*)(ws + 73 * MB);

  split_x_kernel<<<2048, 256, 0, stream>>>(x, xh, xl);
  transpose_w_kernel<<<256, 256, 0, stream>>>(WQ, wqh, wql);
  transpose_w_kernel<<<256, 256, 0, stream>>>(WK, wkh, wkl);
  transpose_w_kernel<<<256, 256, 0, stream>>>(WV, wvh, wvl);

  dim3 gproj(32, 8);
  // Q: scaled by 1/sqrt(D)=1/32 before split; K: unscaled; both split hi/lo.
  proj_kernel<true, true><<<gproj, 256, 0, stream>>>(xh, xl, wqh, wql, bQ,
                                                     1.0f / 32.0f, qh, ql, nullptr);
  proj_kernel<true, true><<<gproj, 256, 0, stream>>>(xh, xl, wkh, wkl, bK,
                                                     1.0f, kh, kl, nullptr);
  // V: single-term bf16 is accurate enough; written transposed for PV.
  proj_kernel<false, false><<<gproj, 256, 0, stream>>>(xh, nullptr, wvh, nullptr, bV,
                                                       1.0f, nullptr, nullptr, vT);

  dim3 gsc(32, 32);
  scores_kernel<<<gsc, 256, 0, stream>>>(qh, ql, kh, kl, P, mloc, tsum);
  finalize_kernel<<<16, 256, 0, stream>>>(mloc, tsum, rowscale);
  pnorm_kernel<<<4096, 256, 0, stream>>>(P, rowscale);

  dim3 gpv(32, 8);
  pv_kernel<<<gpv, 256, 0, stream>>>(P, vT, out);
}

// Round 3
// 334.750 us; speedup vs baseline: 1.0199x; 1.0091x over previous
//
#include <hip/hip_runtime.h>
#include <hip/hip_bf16.h>
#include <stdint.h>

#define SEQLEN 4096
#define DMODEL 1024

typedef uint16_t u16;
typedef uint32_t u32;

typedef __bf16 bf16x8 __attribute__((ext_vector_type(8)));
typedef float  f32x4  __attribute__((ext_vector_type(4)));
typedef u16    u16x8  __attribute__((ext_vector_type(8)));
typedef u16    u16x4  __attribute__((ext_vector_type(4)));

// counted waits + raw barrier (no implicit vmcnt(0) drain — the T4 mechanism)
#define VMCNT8() asm volatile("s_waitcnt vmcnt(8)" ::: "memory")
#define VMCNT0() asm volatile("s_waitcnt vmcnt(0)" ::: "memory")
#define BAR() __builtin_amdgcn_s_barrier()

// ---------------- helpers ----------------
__device__ __forceinline__ u16 f2bf(float f) {
  union { float f; u32 u; } a; a.f = f;
  return (u16)((a.u + 0x7FFFu + ((a.u >> 16) & 1u)) >> 16);  // RNE
}
__device__ __forceinline__ float bf2f(u16 h) {
  union { u32 u; float f; } a; a.u = ((u32)h) << 16;
  return a.f;
}

__device__ __forceinline__ void gl_lds16(const u16* g, u16* l) {
  __builtin_amdgcn_global_load_lds(
      (const __attribute__((address_space(1))) void*)g,
      (__attribute__((address_space(3))) void*)l,
      16, 0, 0);
}

// ---- staging: LDS dest linear (global_load_lds requirement); XOR swizzle
// applied on the per-lane GLOBAL source chunk (rule #21), undone at read.
// 8 gl_lds per thread per K-step in every kernel -> uniform vmcnt(8).
__device__ __forceinline__ void stage64(const u16* __restrict__ g, int ld,
                                        int row0, int k0, u16* lds, int tid) {
#pragma unroll
  for (int it = 0; it < 4; ++it) {
    int u = tid + 256 * it;        // 16B-chunk index 0..1023
    int row = u >> 3;
    int cg = (u & 7) ^ (row & 7);
    gl_lds16(g + (size_t)(row0 + row) * ld + (size_t)(k0 + cg * 8), lds + u * 8);
  }
}
__device__ __forceinline__ void stage32(const u16* __restrict__ g, int ld,
                                        int row0, int k0, u16* lds, int tid) {
#pragma unroll
  for (int it = 0; it < 2; ++it) {
    int u = tid + 256 * it;        // 16B-chunk index 0..511
    int row = u >> 2;
    int cg = (u & 3) ^ ((row >> 1) & 3);
    gl_lds16(g + (size_t)(row0 + row) * ld + (size_t)(k0 + cg * 8), lds + u * 8);
  }
}
__device__ __forceinline__ bf16x8 frag64(const u16* lds, int row, int chunk) {
  return *(const bf16x8*)(lds + row * 64 + ((chunk ^ (row & 7)) << 3));
}
__device__ __forceinline__ bf16x8 frag32(const u16* lds, int row, int chunk) {
  return *(const bf16x8*)(lds + row * 32 + ((chunk ^ ((row >> 1) & 3)) << 3));
}

#define MFMA16(c, a, b) c = __builtin_amdgcn_mfma_f32_16x16x32_bf16(a, b, c, 0, 0, 0)

// ---------------- prep kernels ----------------
__global__ void split_x_kernel(const float* __restrict__ x,
                               u16* __restrict__ xh, u16* __restrict__ xl) {
  const int total = SEQLEN * DMODEL / 4;
  for (int idx = blockIdx.x * 256 + threadIdx.x; idx < total; idx += gridDim.x * 256) {
    float4 f = ((const float4*)x)[idx];
    float ff[4] = {f.x, f.y, f.z, f.w};
    union { u16x4 v; u16 s[4]; } h, l;
#pragma unroll
    for (int uu = 0; uu < 4; ++uu) {
      u16 hi = f2bf(ff[uu]);
      h.s[uu] = hi;
      l.s[uu] = f2bf(ff[uu] - bf2f(hi));
    }
    ((u16x4*)xh)[idx] = h.v;
    ((u16x4*)xl)[idx] = l.v;
  }
}

// W [1024 k][1024 n] fp32 -> WT hi/lo bf16 [1024 n][1024 k]
__global__ void transpose_w_kernel(const float* __restrict__ W,
                                   u16* __restrict__ wth, u16* __restrict__ wtl) {
  __shared__ float tile[64][65];
  int n0 = (blockIdx.x & 15) * 64;
  int k0 = (blockIdx.x >> 4) * 64;
  int c = threadIdx.x & 63, r0 = threadIdx.x >> 6;
#pragma unroll
  for (int rr = 0; rr < 16; ++rr) {
    int r = r0 * 16 + rr;
    tile[r][c] = W[(size_t)(k0 + r) * DMODEL + n0 + c];
  }
  __syncthreads();
#pragma unroll
  for (int rr = 0; rr < 16; ++rr) {
    int n = r0 * 16 + rr;
    float f = tile[c][n];
    u16 hi = f2bf(f);
    wth[(size_t)(n0 + n) * DMODEL + k0 + c] = hi;
    wtl[(size_t)(n0 + n) * DMODEL + k0 + c] = f2bf(f - bf2f(hi));
  }
}

// ---------------- projection GEMM (counted-vmcnt pipeline) ----------------
// C = A@B^T(+bias), A=[4096][1024] hi/lo, B^T given as [n][k] hi/lo.
// THREE: 3-term split accumulation (BK=32). !THREE: single-term (BK=64).
template <bool THREE, bool SPLITOUT>
__global__ __launch_bounds__(256, 2) void proj_kernel(
    const u16* __restrict__ Ah, const u16* __restrict__ Al,
    const u16* __restrict__ Bh, const u16* __restrict__ Bl,
    const float* __restrict__ bias, float scale,
    u16* __restrict__ outh, u16* __restrict__ outl, u16* __restrict__ outT) {
  __shared__ __align__(16) u16 st[32768];  // 64 KB: 2 buffers

  int tid = threadIdx.x;
  int lane = tid & 63, wid = tid >> 6;
  int wr = (wid >> 1) * 64, wc = (wid & 1) * 64;
  int r = lane & 15, g = lane >> 4;
  int m0 = blockIdx.x * 128, n0 = blockIdx.y * 128;

  f32x4 acc[4][4];
#pragma unroll
  for (int i = 0; i < 4; ++i)
#pragma unroll
    for (int j = 0; j < 4; ++j) acc[i][j] = (f32x4){0.f, 0.f, 0.f, 0.f};

  if (THREE) {
    const int NT = DMODEL / 32;
    stage32(Ah, DMODEL, m0, 0, st + 0 * 4096, tid);
    stage32(Al, DMODEL, m0, 0, st + 1 * 4096, tid);
    stage32(Bh, DMODEL, n0, 0, st + 2 * 4096, tid);
    stage32(Bl, DMODEL, n0, 0, st + 3 * 4096, tid);
    stage32(Ah, DMODEL, m0, 32, st + 16384 + 0 * 4096, tid);
    stage32(Al, DMODEL, m0, 32, st + 16384 + 1 * 4096, tid);
    stage32(Bh, DMODEL, n0, 32, st + 16384 + 2 * 4096, tid);
    stage32(Bl, DMODEL, n0, 32, st + 16384 + 3 * 4096, tid);
    for (int t = 0; t < NT; ++t) {
      if (t < NT - 1) VMCNT8(); else VMCNT0();
      BAR();
      const u16* cb = st + (t & 1) * 16384;
      bf16x8 fa[4], fb[4], fal[4], fbl[4];
#pragma unroll
      for (int i = 0; i < 4; ++i) {
        fa[i]  = frag32(cb + 0 * 4096, wr + i * 16 + r, g);
        fal[i] = frag32(cb + 1 * 4096, wr + i * 16 + r, g);
        fb[i]  = frag32(cb + 2 * 4096, wc + i * 16 + r, g);
        fbl[i] = frag32(cb + 3 * 4096, wc + i * 16 + r, g);
      }
#pragma unroll
      for (int i = 0; i < 4; ++i)
#pragma unroll
        for (int j = 0; j < 4; ++j) {
          MFMA16(acc[i][j], fa[i], fb[j]);
          MFMA16(acc[i][j], fa[i], fbl[j]);
          MFMA16(acc[i][j], fal[i], fb[j]);
        }
      BAR();
      if (t + 2 < NT) {
        int k0 = (t + 2) * 32;
        u16* nb = st + (t & 1) * 16384;
        stage32(Ah, DMODEL, m0, k0, nb + 0 * 4096, tid);
        stage32(Al, DMODEL, m0, k0, nb + 1 * 4096, tid);
        stage32(Bh, DMODEL, n0, k0, nb + 2 * 4096, tid);
        stage32(Bl, DMODEL, n0, k0, nb + 3 * 4096, tid);
      }
    }
  } else {
    const int NT = DMODEL / 64;
    stage64(Ah, DMODEL, m0, 0, st + 0 * 8192, tid);
    stage64(Bh, DMODEL, n0, 0, st + 1 * 8192, tid);
    stage64(Ah, DMODEL, m0, 64, st + 16384 + 0 * 8192, tid);
    stage64(Bh, DMODEL, n0, 64, st + 16384 + 1 * 8192, tid);
    for (int t = 0; t < NT; ++t) {
      if (t < NT - 1) VMCNT8(); else VMCNT0();
      BAR();
      const u16* cb = st + (t & 1) * 16384;
#pragma unroll
      for (int ks = 0; ks < 2; ++ks) {
        bf16x8 fa[4], fb[4];
#pragma unroll
        for (int i = 0; i < 4; ++i) {
          fa[i] = frag64(cb + 0 * 8192, wr + i * 16 + r, ks * 4 + g);
          fb[i] = frag64(cb + 1 * 8192, wc + i * 16 + r, ks * 4 + g);
        }
#pragma unroll
        for (int i = 0; i < 4; ++i)
#pragma unroll
          for (int j = 0; j < 4; ++j) MFMA16(acc[i][j], fa[i], fb[j]);
      }
      BAR();
      if (t + 2 < NT) {
        int k0 = (t + 2) * 64;
        u16* nb = st + (t & 1) * 16384;
        stage64(Ah, DMODEL, m0, k0, nb + 0 * 8192, tid);
        stage64(Bh, DMODEL, n0, k0, nb + 1 * 8192, tid);
      }
    }
  }

#pragma unroll
  for (int i = 0; i < 4; ++i)
#pragma unroll
    for (int j = 0; j < 4; ++j) {
      int col = n0 + wc + j * 16 + r;
      float bv = bias[col];
#pragma unroll
      for (int t = 0; t < 4; ++t) {
        int row = m0 + wr + i * 16 + g * 4 + t;
        float v = (acc[i][j][t] + bv) * scale;
        if (SPLITOUT) {
          u16 hi = f2bf(v);
          outh[(size_t)row * DMODEL + col] = hi;
          outl[(size_t)row * DMODEL + col] = f2bf(v - bf2f(hi));
        } else {
          outT[(size_t)col * SEQLEN + row] = f2bf(v);  // transposed V
        }
      }
    }
}

// ---------------- scores + per-tile softmax (counted-vmcnt pipeline) --------
__global__ __launch_bounds__(256, 2) void scores_kernel(
    const u16* __restrict__ qh, const u16* __restrict__ ql,
    const u16* __restrict__ kh, const u16* __restrict__ kl,
    u16* __restrict__ P, float* __restrict__ mloc, float* __restrict__ tsum) {
  // 66048 B: staging (2 buf x 4 tiles x 8 KB = 64 KB) aliased with fp32 S tile
  __shared__ __align__(16) char smem[128 * 129 * 4];
  u16* st = (u16*)smem;
  float* sS = (float*)smem;

  int tid = threadIdx.x;
  int lane = tid & 63, wid = tid >> 6;
  int wr = (wid >> 1) * 64, wc = (wid & 1) * 64;
  int r = lane & 15, g = lane >> 4;
  int m0 = blockIdx.x * 128, n0 = blockIdx.y * 128;

  f32x4 acc[4][4];
#pragma unroll
  for (int i = 0; i < 4; ++i)
#pragma unroll
    for (int j = 0; j < 4; ++j) acc[i][j] = (f32x4){0.f, 0.f, 0.f, 0.f};

  const int NT = DMODEL / 32;
  stage32(qh, DMODEL, m0, 0, st + 0 * 4096, tid);
  stage32(ql, DMODEL, m0, 0, st + 1 * 4096, tid);
  stage32(kh, DMODEL, n0, 0, st + 2 * 4096, tid);
  stage32(kl, DMODEL, n0, 0, st + 3 * 4096, tid);
  stage32(qh, DMODEL, m0, 32, st + 16384 + 0 * 4096, tid);
  stage32(ql, DMODEL, m0, 32, st + 16384 + 1 * 4096, tid);
  stage32(kh, DMODEL, n0, 32, st + 16384 + 2 * 4096, tid);
  stage32(kl, DMODEL, n0, 32, st + 16384 + 3 * 4096, tid);
  for (int t = 0; t < NT; ++t) {
    if (t < NT - 1) VMCNT8(); else VMCNT0();
    BAR();
    const u16* cb = st + (t & 1) * 16384;
    bf16x8 fa[4], fb[4], fal[4], fbl[4];
#pragma unroll
    for (int i = 0; i < 4; ++i) {
      fa[i]  = frag32(cb + 0 * 4096, wr + i * 16 + r, g);
      fal[i] = frag32(cb + 1 * 4096, wr + i * 16 + r, g);
      fb[i]  = frag32(cb + 2 * 4096, wc + i * 16 + r, g);
      fbl[i] = frag32(cb + 3 * 4096, wc + i * 16 + r, g);
    }
#pragma unroll
    for (int i = 0; i < 4; ++i)
#pragma unroll
      for (int j = 0; j < 4; ++j) {
        MFMA16(acc[i][j], fa[i], fb[j]);
        MFMA16(acc[i][j], fa[i], fbl[j]);
        MFMA16(acc[i][j], fal[i], fb[j]);
      }
    BAR();
    if (t + 2 < NT) {
      int k0 = (t + 2) * 32;
      u16* nb = st + (t & 1) * 16384;
      stage32(qh, DMODEL, m0, k0, nb + 0 * 4096, tid);
      stage32(ql, DMODEL, m0, k0, nb + 1 * 4096, tid);
      stage32(kh, DMODEL, n0, k0, nb + 2 * 4096, tid);
      stage32(kl, DMODEL, n0, k0, nb + 3 * 4096, tid);
    }
  }

  // after final bottom barrier all staging reads are consumed; reuse LDS as S
#pragma unroll
  for (int i = 0; i < 4; ++i)
#pragma unroll
    for (int j = 0; j < 4; ++j)
#pragma unroll
      for (int t = 0; t < 4; ++t)
        sS[(wr + i * 16 + g * 4 + t) * 129 + wc + j * 16 + r] = acc[i][j][t];
  __syncthreads();

  int rt = tid >> 1, h = tid & 1;  // 2 threads per row, 64 cols each
  const float* rowp = sS + rt * 129 + h * 64;
  float mx = -3.0e38f;
#pragma unroll 16
  for (int cc = 0; cc < 64; ++cc) mx = fmaxf(mx, rowp[cc]);
  mx = fmaxf(mx, __shfl_xor(mx, 1));

  float ssum = 0.f;
  int grow = m0 + rt;
  u16* pout = P + (size_t)grow * SEQLEN + n0 + h * 64;
#pragma unroll
  for (int c8 = 0; c8 < 8; ++c8) {
    union { u16 s[8]; u16x8 v; } tmp;
#pragma unroll
    for (int uu = 0; uu < 8; ++uu) {
      float e = exp2f((rowp[c8 * 8 + uu] - mx) * 1.4426950408889634f);
      ssum += e;
      tmp.s[uu] = f2bf(e);
    }
    *(u16x8*)(pout + c8 * 8) = tmp.v;
  }
  ssum += __shfl_xor(ssum, 1);
  if (h == 0) {
    mloc[(size_t)blockIdx.y * SEQLEN + grow] = mx;
    tsum[(size_t)blockIdx.y * SEQLEN + grow] = ssum;
  }
}

// ---------------- softmax finalize ----------------
__global__ void finalize_kernel(const float* __restrict__ mloc,
                                const float* __restrict__ tsum,
                                float* __restrict__ rowscale) {
  int rr = blockIdx.x * 256 + threadIdx.x;
  if (rr >= SEQLEN) return;
  float M = -3.0e38f;
#pragma unroll
  for (int t = 0; t < 32; ++t) M = fmaxf(M, mloc[t * SEQLEN + rr]);
  float l = 0.f;
#pragma unroll
  for (int t = 0; t < 32; ++t)
    l += tsum[t * SEQLEN + rr] * exp2f((mloc[t * SEQLEN + rr] - M) * 1.4426950408889634f);
  float inv = 1.0f / l;
#pragma unroll
  for (int t = 0; t < 32; ++t)
    rowscale[t * SEQLEN + rr] = exp2f((mloc[t * SEQLEN + rr] - M) * 1.4426950408889634f) * inv;
}

__global__ void pnorm_kernel(u16* __restrict__ P, const float* __restrict__ rowscale) {
  const int total = SEQLEN * SEQLEN / 8;
  for (int idx = blockIdx.x * 256 + threadIdx.x; idx < total; idx += gridDim.x * 256) {
    int rrow = idx >> 9;
    int c8 = idx & 511;
    int t = c8 >> 4;
    float sc = rowscale[t * SEQLEN + rrow];
    union { u16x8 v; u16 s[8]; } d;
    d.v = ((u16x8*)P)[idx];
#pragma unroll
    for (int uu = 0; uu < 8; ++uu) d.s[uu] = f2bf(bf2f(d.s[uu]) * sc);
    ((u16x8*)P)[idx] = d.v;
  }
}

// ---------------- PV GEMM (counted-vmcnt pipeline) ----------------
__global__ __launch_bounds__(256, 2) void pv_kernel(const u16* __restrict__ P,
                                                    const u16* __restrict__ vT,
                                                    float* __restrict__ out) {
  __shared__ __align__(16) u16 st[32768];  // 64 KB: 2 buffers x [A(16KB), B(16KB)]
  int tid = threadIdx.x;
  int lane = tid & 63, wid = tid >> 6;
  int wr = (wid >> 1) * 64, wc = (wid & 1) * 64;
  int r = lane & 15, g = lane >> 4;
  int m0 = blockIdx.x * 128, n0 = blockIdx.y * 128;

  f32x4 acc[4][4];
#pragma unroll
  for (int i = 0; i < 4; ++i)
#pragma unroll
    for (int j = 0; j < 4; ++j) acc[i][j] = (f32x4){0.f, 0.f, 0.f, 0.f};

  const int NT = SEQLEN / 64;
  stage64(P, SEQLEN, m0, 0, st + 0 * 8192, tid);
  stage64(vT, SEQLEN, n0, 0, st + 1 * 8192, tid);
  stage64(P, SEQLEN, m0, 64, st + 16384 + 0 * 8192, tid);
  stage64(vT, SEQLEN, n0, 64, st + 16384 + 1 * 8192, tid);
  for (int t = 0; t < NT; ++t) {
    if (t < NT - 1) VMCNT8(); else VMCNT0();
    BAR();
    const u16* cb = st + (t & 1) * 16384;
#pragma unroll
    for (int ks = 0; ks < 2; ++ks) {
      bf16x8 fa[4], fb[4];
#pragma unroll
      for (int i = 0; i < 4; ++i) {
        fa[i] = frag64(cb + 0 * 8192, wr + i * 16 + r, ks * 4 + g);
        fb[i] = frag64(cb + 1 * 8192, wc + i * 16 + r, ks * 4 + g);
      }
#pragma unroll
      for (int i = 0; i < 4; ++i)
#pragma unroll
        for (int j = 0; j < 4; ++j) MFMA16(acc[i][j], fa[i], fb[j]);
    }
    BAR();
    if (t + 2 < NT) {
      int k0 = (t + 2) * 64;
      u16* nb = st + (t & 1) * 16384;
      stage64(P, SEQLEN, m0, k0, nb + 0 * 8192, tid);
      stage64(vT, SEQLEN, n0, k0, nb + 1 * 8192, tid);
    }
  }
#pragma unroll
  for (int i = 0; i < 4; ++i)
#pragma unroll
    for (int j = 0; j < 4; ++j)
#pragma unroll
      for (int t = 0; t < 4; ++t)
        out[(size_t)(m0 + wr + i * 16 + g * 4 + t) * DMODEL + n0 + wc + j * 16 + r] =
            acc[i][j][t];
}

// ---------------- launch ----------------
extern "C" void kernel_launch(void* const* d_in, const int* in_sizes, int n_in,
                              void* d_out, int out_size, void* d_ws, size_t ws_size,
                              hipStream_t stream) {
  (void)in_sizes; (void)n_in; (void)out_size; (void)ws_size;
  const float* x  = (const float*)d_in[0];
  const float* WQ = (const float*)d_in[1];
  const float* WK = (const float*)d_in[2];
  const float* WV = (const float*)d_in[3];
  const float* bQ = (const float*)d_in[4];
  const float* bK = (const float*)d_in[5];
  const float* bV = (const float*)d_in[6];
  float* out = (float*)d_out;
  char* ws = (char*)d_ws;
  const size_t MB = 1ull << 20;

  // Prep region [0,28MB) is dead after projections; P (32MB) overlays it.
  u16* xh   = (u16*)(ws + 0);
  u16* xl   = (u16*)(ws + 8 * MB);
  u16* wqh  = (u16*)(ws + 16 * MB);
  u16* wql  = (u16*)(ws + 18 * MB);
  u16* wkh  = (u16*)(ws + 20 * MB);
  u16* wkl  = (u16*)(ws + 22 * MB);
  u16* wvh  = (u16*)(ws + 24 * MB);
  u16* wvl  = (u16*)(ws + 26 * MB);
  u16* P    = (u16*)(ws + 0);  // 32MB, written after prep region is dead
  u16* qh   = (u16*)(ws + 32 * MB);
  u16* ql   = (u16*)(ws + 40 * MB);
  u16* kh   = (u16*)(ws + 48 * MB);
  u16* kl   = (u16*)(ws + 56 * MB);
  u16* vT   = (u16*)(ws + 64 * MB);
  float* mloc     = (float*)(ws + 72 * MB);
  float* tsum     = (float*)(ws + 72 * MB + 512 * 1024);
  float* rowscale = (float*)(ws + 73 * MB);

  split_x_kernel<<<2048, 256, 0, stream>>>(x, xh, xl);
  transpose_w_kernel<<<256, 256, 0, stream>>>(WQ, wqh, wql);
  transpose_w_kernel<<<256, 256, 0, stream>>>(WK, wkh, wkl);
  transpose_w_kernel<<<256, 256, 0, stream>>>(WV, wvh, wvl);

  dim3 gproj(32, 8);
  // Q: scaled by 1/sqrt(D)=1/32 before split; K: unscaled; both split hi/lo.
  proj_kernel<true, true><<<gproj, 256, 0, stream>>>(xh, xl, wqh, wql, bQ,
                                                     1.0f / 32.0f, qh, ql, nullptr);
  proj_kernel<true, true><<<gproj, 256, 0, stream>>>(xh, xl, wkh, wkl, bK,
                                                     1.0f, kh, kl, nullptr);
  // V: single-term bf16 is accurate enough; written transposed for PV.
  proj_kernel<false, false><<<gproj, 256, 0, stream>>>(xh, nullptr, wvh, nullptr, bV,
                                                       1.0f, nullptr, nullptr, vT);

  dim3 gsc(32, 32);
  scores_kernel<<<gsc, 256, 0, stream>>>(qh, ql, kh, kl, P, mloc, tsum);
  finalize_kernel<<<16, 256, 0, stream>>>(mloc, tsum, rowscale);
  pnorm_kernel<<<4096, 256, 0, stream>>>(P, rowscale);

  dim3 gpv(32, 8);
  pv_kernel<<<gpv, 256, 0, stream>>>(P, vT, out);
}